// Round 5
// baseline (728.058 us; speedup 1.0000x reference)
//
#include <hip/hip_runtime.h>
#include <stdint.h>

typedef short bf16x8 __attribute__((ext_vector_type(8)));
typedef float f32x4 __attribute__((ext_vector_type(4)));

// ---------------------------------------------------------------------------
// Threefry-2x32 (JAX/Random123 schedule)
// ---------------------------------------------------------------------------
__host__ __device__ inline uint32_t rotl32(uint32_t v, int d) {
  return (v << d) | (v >> (32 - d));
}

__host__ __device__ inline void tf2x32(uint32_t k0, uint32_t k1,
                                       uint32_t x0, uint32_t x1,
                                       uint32_t& o0, uint32_t& o1) {
  uint32_t ks0 = k0, ks1 = k1, ks2 = k0 ^ k1 ^ 0x1BD11BDAu;
  x0 += ks0; x1 += ks1;
#define TF_R(r) { x0 += x1; x1 = rotl32(x1, (r)); x1 ^= x0; }
  TF_R(13) TF_R(15) TF_R(26) TF_R(6)
  x0 += ks1; x1 += ks2 + 1u;
  TF_R(17) TF_R(29) TF_R(16) TF_R(24)
  x0 += ks2; x1 += ks0 + 2u;
  TF_R(13) TF_R(15) TF_R(26) TF_R(6)
  x0 += ks0; x1 += ks1 + 3u;
  TF_R(17) TF_R(29) TF_R(16) TF_R(24)
  x0 += ks1; x1 += ks2 + 4u;
  TF_R(13) TF_R(15) TF_R(26) TF_R(6)
  x0 += ks2; x1 += ks0 + 5u;
#undef TF_R
  o0 = x0; o1 = x1;
}

// XLA's fp32 erf_inv (Giles polynomial); log1p via fast v_log path
__device__ __forceinline__ float erfinv_xla(float x) {
  float w = -__logf(fmaf(-x, x, 1.0f));
  float p;
  if (w < 5.0f) {
    w = w - 2.5f;
    p = 2.81022636e-08f;
    p = fmaf(p, w, 3.43273939e-07f);
    p = fmaf(p, w, -3.5233877e-06f);
    p = fmaf(p, w, -4.39150654e-06f);
    p = fmaf(p, w, 0.00021858087f);
    p = fmaf(p, w, -0.00125372503f);
    p = fmaf(p, w, -0.00417768164f);
    p = fmaf(p, w, 0.246640727f);
    p = fmaf(p, w, 1.50140941f);
  } else {
    w = sqrtf(w) - 3.0f;
    p = -0.000200214257f;
    p = fmaf(p, w, 0.000100950558f);
    p = fmaf(p, w, 0.00134934322f);
    p = fmaf(p, w, -0.00367342844f);
    p = fmaf(p, w, 0.00573950773f);
    p = fmaf(p, w, -0.0076224613f);
    p = fmaf(p, w, 0.00943887047f);
    p = fmaf(p, w, 1.00167406f);
    p = fmaf(p, w, 2.83297682f);
  }
  return p * x;
}

__device__ __forceinline__ float bits_to_normal(uint32_t bits) {
  uint32_t fb = (bits >> 9) | 0x3F800000u;
  float f = __uint_as_float(fb) - 1.0f;
  const float lo = -0.99999994f;
  float u = fmaf(f, 1.0f - lo, lo);
  u = fmaxf(lo, u);
  return 1.41421356f * erfinv_xla(u);
}

// packed f32x2 -> bf16x2 RNE in ONE instruction
__device__ __forceinline__ uint32_t cvt_pk_bf16(float lo, float hi) {
  uint32_t r;
  asm("v_cvt_pk_bf16_f32 %0, %1, %2" : "=v"(r) : "v"(lo), "v"(hi));
  return r;
}

__device__ __forceinline__ float bf2f_s(short h) {
  return __uint_as_float(((uint32_t)(uint16_t)h) << 16);
}

// pack 8 f32 -> bf16x8 via RNE (4 cvt_pk)
__device__ __forceinline__ bf16x8 pack8(const float (&r)[8]) {
  union { bf16x8 v; uint32_t u[4]; } o;
#pragma unroll
  for (int p = 0; p < 4; ++p)
    o.u[p] = cvt_pk_bf16(r[2 * p], r[2 * p + 1]);
  return o.v;
}

// branchless sorted-descending top-T insert (med3/min3 form)
template <int T>
__device__ __forceinline__ void insT(float (&t)[T], float v) {
  if constexpr (T == 1) {
    t[0] = fmaxf(t[0], v);
  } else {
    float t0o = t[0], t1o = t[1];
    t[0] = fmaxf(t0o, v);
    t[1] = __builtin_amdgcn_fmed3f(v, t0o, t1o);
    float a = fminf(fminf(v, t0o), t1o);   // fuses to v_min3_f32
#pragma unroll
    for (int q = 2; q < T; ++q) {
      float tq = t[q];
      t[q] = fmaxf(tq, a);
      a = fminf(tq, a);
    }
  }
}

// ---------------------------------------------------------------------------
// MFMA worker. Block = one combo row-pair (rp, rp+512). 2 sample-passes of 64.
// Swapped MFMA (D col = sample). B tiles (ks,nf) loaded direct from global via
// a depth-D REGISTER ring pipeline: tile p consumed from buf[p%D], then the
// same buffer is reloaded with tile p+D (WAR/RAW reg deps make the pipeline
// compiler-proof; counted vmcnt keeps D-1 tiles in flight -> HBM latency
// hidden by ~(D-1) steps x 4 waves/SIMD). Prologue tiles issued BEFORE genX
// so they fly under the RNG burst. Zero LDS in the Y loop, zero extra
// barriers, bounded reg payload (no R1-style spills). T = m+1.
// ---------------------------------------------------------------------------
template <int K, int KP, int T>
__device__ void process_combo(const float* __restrict__ Pp,
                              const float* __restrict__ yp,
                              const float* __restrict__ yt,
                              float* __restrict__ accum,
                              int ofs, uint32_t key0, uint32_t key1,
                              int rp, char* sm) {
  constexpr int KSTEPS = KP / 32;
  constexpr int NCH = (K + 31) / 32;
  constexpr int PH = K / 2;            // k-pairs per sample per row
  constexpr int ITERS = PH / 4;        // genX iters (64*PH/256)
  constexpr int XSTR = KP + 8;         // bf16 elems per sample row (+16B pad)
  constexpr int XSTRU = XSTR / 2;      // uints per sample row
  constexpr int XROW_U = 64 * XSTRU;   // uints per data-row section
  constexpr int REGION = 2 * 64 * XSTR * 2;  // X both rows (bytes)
  // last chunk's nf=1 16-col subtile lies entirely in [K,K+16) padding:
  // we still LOAD/MFMA it (uniform pipeline) but exclude it from top-T.
  constexpr bool SKIP1 = (K % 32) == 16;
  constexpr uint32_t HALF = 65536u * (uint32_t)K;
  constexpr int TPC = 2 * KSTEPS;              // tiles per chunk
  constexpr int DD = (TPC % 4 == 0) ? 4 : 3;   // ring depth; TPC % DD == 0

  const int tid = threadIdx.x;
  const int wave = tid >> 6;
  const int lane = tid & 63;
  const int quad = lane >> 4;
  const int l15 = lane & 15;
  const int row = wave >> 1;           // data-row of this wave (0/1)
  const int msub = (wave & 1) * 32;    // sample offset of this wave

  const int b0 = 4 * rp + ofs;
  const int b1 = 4 * (rp + 512) + ofs;

  uint32_t* Xu = (uint32_t*)sm;            // X both rows
  float* wvmax = (float*)(sm + REGION);    // 4 floats
  float* maxhm = wvmax + 4;                // 2 floats

  if (tid < 2) maxhm[tid] = 0.0f;

  // this wave's P base: quad selects k-subrow group, l15 selects column
  const float* Pr = Pp + (size_t)(row ? b1 : b0) * 16384 + quad * (8 * 128) + l15;

  for (int pass = 0; pass < 2; ++pass) {
    // ---- pipeline prologue: first DD tiles of chunk 0, issued BEFORE genX
    // so the loads complete under the RNG burst. Reg payload: DD*8 floats.
    float buf0[8], buf1[8], buf2[8], buf3[8];
#pragma unroll
    for (int j = 0; j < 8; ++j) buf0[j] = Pr[j * 128];            // (ks0,nf0)
#pragma unroll
    for (int j = 0; j < 8; ++j) buf1[j] = Pr[16 + j * 128];       // (ks0,nf1)
#pragma unroll
    for (int j = 0; j < 8; ++j) buf2[j] = Pr[4096 + j * 128];     // (ks1,nf0)
    if constexpr (DD == 4) {
#pragma unroll
      for (int j = 0; j < 8; ++j) buf3[j] = Pr[4096 + 16 + j * 128]; // (ks1,nf1)
    }

    // ---- Phase A: generate X (both rows) straight to LDS as bf16
#pragma unroll
    for (int it = 0; it < ITERS; ++it) {
      int q = it * 256 + tid;
      int s_loc = q / PH;
      int k = 2 * (q - s_loc * PH);
      uint32_t ctr = (uint32_t)((rp * 128 + pass * 64 + s_loc) * K + k);
      uint32_t o0a, o1a, o0b, o1b;
      tf2x32(key0, key1, ctr, ctr + HALF, o0a, o1a);
      tf2x32(key0, key1, ctr + 1u, ctr + 1u + HALF, o0b, o1b);
      uint32_t idx = (uint32_t)(s_loc * XSTRU + (k >> 1));
      Xu[idx]          = cvt_pk_bf16(bits_to_normal(o0a), bits_to_normal(o0b));
      Xu[XROW_U + idx] = cvt_pk_bf16(bits_to_normal(o1a), bits_to_normal(o1b));
    }
    if constexpr (KP > K) {   // zero-pad k in [K,KP) for both rows
      constexpr int PADU = (KP - K) / 2;
      for (int p = tid; p < 2 * 64 * PADU; p += 256) {
        int rs = p / PADU;
        int r = p - rs * PADU;
        Xu[rs * XSTRU + K / 2 + r] = 0;
      }
    }
    __syncthreads();   // s1: X visible (cross-wave)

    // ---- X-frag load (MFMA B-operand) + per-lane X partial top-T (k-slice)
    bf16x8 ahi[2][KSTEPS];
#pragma unroll
    for (int f = 0; f < 2; ++f)
#pragma unroll
      for (int ks = 0; ks < KSTEPS; ++ks) {
        int off = ((row * 64 + msub + f * 16 + l15) * XSTR + ks * 32 + quad * 8) * 2;
        ahi[f][ks] = *(const bf16x8*)(sm + off);
      }
    float t5x[2][T];
#pragma unroll
    for (int f = 0; f < 2; ++f) {
#pragma unroll
      for (int q = 0; q < T; ++q) t5x[f][q] = 0.0f;
#pragma unroll
      for (int ks = 0; ks < KSTEPS; ++ks)
#pragma unroll
        for (int j = 0; j < 8; ++j)
          insT(t5x[f], fabsf(bf2f_s(ahi[f][ks][j])));
    }

    // ---- Y chunks: depth-DD register-ring pipeline, barrier-free
    float t5y[2][T];
#pragma unroll
    for (int f = 0; f < 2; ++f)
#pragma unroll
      for (int q = 0; q < T; ++q) t5y[f][q] = 0.0f;

#pragma unroll 1
    for (int c = 0; c < NCH; ++c) {
      const float* bpc = Pr + c * 32;
      const float* bpn = Pr + (c + 1 < NCH ? c + 1 : c) * 32;  // clamped
      f32x4 acc[2][2];
#pragma unroll
      for (int f = 0; f < 2; ++f)
#pragma unroll
        for (int nf = 0; nf < 2; ++nf) acc[f][nf] = (f32x4){0.f, 0.f, 0.f, 0.f};

      // one pipeline step: consume tile p from buf, refill buf with tile p+DD
      auto step = [&](int p, float (&buf)[8]) {
        const int ks = p >> 1, nf = p & 1;
        bf16x8 bh = pack8(buf);            // waits only this buffer's loads
        const int p2 = p + DD;
        const float* na = (p2 < TPC)
            ? (bpc + (p2 >> 1) * 4096 + (p2 & 1) * 16)
            : (bpn + ((p2 - TPC) >> 1) * 4096 + ((p2 - TPC) & 1) * 16);
#pragma unroll
        for (int j = 0; j < 8; ++j) buf[j] = na[j * 128];   // refill (WAR-safe)
        acc[0][nf] = __builtin_amdgcn_mfma_f32_16x16x32_bf16(bh, ahi[0][ks], acc[0][nf], 0, 0, 0);
        acc[1][nf] = __builtin_amdgcn_mfma_f32_16x16x32_bf16(bh, ahi[1][ks], acc[1][nf], 0, 0, 0);
      };
#pragma unroll
      for (int pb = 0; pb < TPC; pb += DD) {
        step(pb + 0, buf0);
        step(pb + 1, buf1);
        step(pb + 2, buf2);
        if constexpr (DD == 4) step(pb + 3, buf3);
      }

      // per-chunk top-T fold (junk nf=1 subtile of skip1 chunk excluded)
      const bool skip1 = SKIP1 && (c == NCH - 1);
#pragma unroll
      for (int f = 0; f < 2; ++f)
#pragma unroll
        for (int r = 0; r < 4; ++r) {
          insT(t5y[f], fabsf(acc[f][0][r]));
          if (!skip1) insT(t5y[f], fabsf(acc[f][1][r]));
        }
    }

    // ---- merge: fold X partials, ONE quad butterfly (16,32), hm, wave max
    float wmax = 0.0f;
#pragma unroll
    for (int f = 0; f < 2; ++f) {
#pragma unroll
      for (int q = 0; q < T; ++q) insT(t5y[f], t5x[f][q]);
#pragma unroll
      for (int msk = 16; msk <= 32; msk <<= 1) {
        float o[T];
#pragma unroll
        for (int q = 0; q < T; ++q) o[q] = __shfl_xor(t5y[f][q], msk);
#pragma unroll
        for (int q = 0; q < T; ++q) insT(t5y[f], o[q]);
      }
      float hm = t5y[f][0] / (t5y[f][T - 1] + 1e-9f);
      wmax = fmaxf(wmax, hm);
    }
    // values replicated across quads; reduce across l15
#pragma unroll
    for (int msk = 1; msk <= 8; msk <<= 1)
      wmax = fmaxf(wmax, __shfl_xor(wmax, msk));
    if (lane == 0) wvmax[wave] = wmax;
    __syncthreads();   // s2: wvmax visible; also guards X reads vs next genX
    if (tid < 2)
      maxhm[tid] = fmaxf(maxhm[tid], fmaxf(wvmax[2 * tid], wvmax[2 * tid + 1]));
  }

  if (tid == 0) {
    float pen = fmaxf(maxhm[0] - yp[b0], 0.0f) + fmaxf(maxhm[1] - yp[b1], 0.0f);
    atomicAdd(&accum[0], pen);
    float d0 = log2f(fmaxf(yt[b0], 1e-9f)) - log2f(fmaxf(yp[b0], 1e-9f));
    float d1 = log2f(fmaxf(yt[b1], 1e-9f)) - log2f(fmaxf(yp[b1], 1e-9f));
    atomicAdd(&accum[1], fmaf(d0, d0, d1 * d1));
  }
}

struct ComboArgs {
  int ofs[4];
  uint32_t k0[4];
  uint32_t k1[4];
};

// max REGION (KP=128: 34816) + wvmax(16) + maxhm(8)
#define SM_BYTES (34816 + 16 + 8)

// (256,2): VGPR cap 256 -> compiler picks <=128, matching 4 blocks/CU
// (16 waves/CU; VGPR>64 caps at 16 waves/CU regardless of LDS).
__global__ __launch_bounds__(256, 2)
void viol_kernel(const float* __restrict__ Pp, const float* __restrict__ yp,
                 const float* __restrict__ yt, float* __restrict__ accum,
                 ComboArgs ca) {
  __shared__ __align__(16) char sm[SM_BYTES];
  // 512 contiguous blocks per combo (measured-good: L2 locality on P rows)
  int i = blockIdx.x >> 9;
  int rp = blockIdx.x & 511;
  switch (i) {
    case 0: process_combo< 80,  96, 3>(Pp, yp, yt, accum, ca.ofs[0], ca.k0[0], ca.k1[0], rp, sm); break;
    case 1: process_combo< 96,  96, 4>(Pp, yp, yt, accum, ca.ofs[1], ca.k0[1], ca.k1[1], rp, sm); break;
    case 2: process_combo<112, 128, 5>(Pp, yp, yt, accum, ca.ofs[2], ca.k0[2], ca.k1[2], rp, sm); break;
    default: process_combo<128, 128, 4>(Pp, yp, yt, accum, ca.ofs[3], ca.k0[3], ca.k1[3], rp, sm); break;
  }
}

__global__ void finalize_kernel(const float* __restrict__ accum, float* __restrict__ out) {
  if (threadIdx.x == 0 && blockIdx.x == 0) {
    float viol = accum[0] / 4096.0f;
    float lm = accum[1] / 4096.0f;
    out[0] = fmaf(0.5f, viol, lm);
    out[1] = lm;
    out[2] = viol;
  }
}

extern "C" void kernel_launch(void* const* d_in, const int* in_sizes, int n_in,
                              void* d_out, int out_size, void* d_ws, size_t ws_size,
                              hipStream_t stream) {
  const float* y_pred   = (const float*)d_in[0];
  const float* y_true   = (const float*)d_in[1];
  const float* P_padded = (const float*)d_in[2];
  float* accum = (float*)d_ws;
  float* out = (float*)d_out;

  hipMemsetAsync(accum, 0, 2 * sizeof(float), stream);

  // combos sorted as np.unique: (160,80,2)<-b%4==3, (192,96,3)<-1, (224,112,4)<-2, (256,128,3)<-0
  ComboArgs ca;
  const int ofs[4] = {3, 1, 2, 0};
  for (int i = 0; i < 4; ++i) {
    ca.ofs[i] = ofs[i];
    uint32_t o0, o1;
    tf2x32(0u, 42u, 0u, (uint32_t)i, o0, o1);  // fold_in(key(42), i)
    ca.k0[i] = o0;
    ca.k1[i] = o1;
  }

  viol_kernel<<<2048, 256, 0, stream>>>(P_padded, y_pred, y_true, accum, ca);
  finalize_kernel<<<1, 64, 0, stream>>>(accum, out);
}

// Round 6
// 456.017 us; speedup vs baseline: 1.5966x; 1.5966x over previous
//
#include <hip/hip_runtime.h>
#include <stdint.h>

typedef short bf16x8 __attribute__((ext_vector_type(8)));
typedef float f32x4 __attribute__((ext_vector_type(4)));

// ---------------------------------------------------------------------------
// Threefry-2x32 (JAX/Random123 schedule)
// ---------------------------------------------------------------------------
__host__ __device__ inline uint32_t rotl32(uint32_t v, int d) {
  return (v << d) | (v >> (32 - d));
}

__host__ __device__ inline void tf2x32(uint32_t k0, uint32_t k1,
                                       uint32_t x0, uint32_t x1,
                                       uint32_t& o0, uint32_t& o1) {
  uint32_t ks0 = k0, ks1 = k1, ks2 = k0 ^ k1 ^ 0x1BD11BDAu;
  x0 += ks0; x1 += ks1;
#define TF_R(r) { x0 += x1; x1 = rotl32(x1, (r)); x1 ^= x0; }
  TF_R(13) TF_R(15) TF_R(26) TF_R(6)
  x0 += ks1; x1 += ks2 + 1u;
  TF_R(17) TF_R(29) TF_R(16) TF_R(24)
  x0 += ks2; x1 += ks0 + 2u;
  TF_R(13) TF_R(15) TF_R(26) TF_R(6)
  x0 += ks0; x1 += ks1 + 3u;
  TF_R(17) TF_R(29) TF_R(16) TF_R(24)
  x0 += ks1; x1 += ks2 + 4u;
  TF_R(13) TF_R(15) TF_R(26) TF_R(6)
  x0 += ks2; x1 += ks0 + 5u;
#undef TF_R
  o0 = x0; o1 = x1;
}

// XLA's fp32 erf_inv (Giles polynomial); log1p via fast v_log path
__device__ __forceinline__ float erfinv_xla(float x) {
  float w = -__logf(fmaf(-x, x, 1.0f));
  float p;
  if (w < 5.0f) {
    w = w - 2.5f;
    p = 2.81022636e-08f;
    p = fmaf(p, w, 3.43273939e-07f);
    p = fmaf(p, w, -3.5233877e-06f);
    p = fmaf(p, w, -4.39150654e-06f);
    p = fmaf(p, w, 0.00021858087f);
    p = fmaf(p, w, -0.00125372503f);
    p = fmaf(p, w, -0.00417768164f);
    p = fmaf(p, w, 0.246640727f);
    p = fmaf(p, w, 1.50140941f);
  } else {
    w = sqrtf(w) - 3.0f;
    p = -0.000200214257f;
    p = fmaf(p, w, 0.000100950558f);
    p = fmaf(p, w, 0.00134934322f);
    p = fmaf(p, w, -0.00367342844f);
    p = fmaf(p, w, 0.00573950773f);
    p = fmaf(p, w, -0.0076224613f);
    p = fmaf(p, w, 0.00943887047f);
    p = fmaf(p, w, 1.00167406f);
    p = fmaf(p, w, 2.83297682f);
  }
  return p * x;
}

__device__ __forceinline__ float bits_to_normal(uint32_t bits) {
  uint32_t fb = (bits >> 9) | 0x3F800000u;
  float f = __uint_as_float(fb) - 1.0f;
  const float lo = -0.99999994f;
  float u = fmaf(f, 1.0f - lo, lo);
  u = fmaxf(lo, u);
  return 1.41421356f * erfinv_xla(u);
}

// packed f32x2 -> bf16x2 RNE in ONE instruction
__device__ __forceinline__ uint32_t cvt_pk_bf16(float lo, float hi) {
  uint32_t r;
  asm("v_cvt_pk_bf16_f32 %0, %1, %2" : "=v"(r) : "v"(lo), "v"(hi));
  return r;
}

__device__ __forceinline__ float bf2f_s(short h) {
  return __uint_as_float(((uint32_t)(uint16_t)h) << 16);
}

// pack 8 f32 -> bf16x8 via RNE (4 cvt_pk)
__device__ __forceinline__ bf16x8 pack8(const float (&r)[8]) {
  union { bf16x8 v; uint32_t u[4]; } o;
#pragma unroll
  for (int p = 0; p < 4; ++p)
    o.u[p] = cvt_pk_bf16(r[2 * p], r[2 * p + 1]);
  return o.v;
}

// branchless sorted-descending top-T insert (med3/min3 form)
template <int T>
__device__ __forceinline__ void insT(float (&t)[T], float v) {
  if constexpr (T == 1) {
    t[0] = fmaxf(t[0], v);
  } else {
    float t0o = t[0], t1o = t[1];
    t[0] = fmaxf(t0o, v);
    t[1] = __builtin_amdgcn_fmed3f(v, t0o, t1o);
    float a = fminf(fminf(v, t0o), t1o);   // fuses to v_min3_f32
#pragma unroll
    for (int q = 2; q < T; ++q) {
      float tq = t[q];
      t[q] = fmaxf(tq, a);
      a = fminf(tq, a);
    }
  }
}

// ---------------------------------------------------------------------------
// MFMA worker. Block = one combo row-pair (rp, rp+512). 2 sample-passes of 64.
// Swapped MFMA (D col = sample). R4 structure (verified 196us) with ONE
// change: B loads are issued in 2-ks GROUPS (up to 32 dwords) before any
// pack8/MFMA consumes them — straight-line issue-before-consume so all group
// loads are in flight at the first wait, and later tiles' latency hides
// under earlier tiles' cvt+MFMA. No loop-carried payload (R1 lesson), no
// reg-ring (R5 lesson: hand pipelines serialize). T = m+1.
// ---------------------------------------------------------------------------
template <int K, int KP, int T>
__device__ void process_combo(const float* __restrict__ Pp,
                              const float* __restrict__ yp,
                              const float* __restrict__ yt,
                              float* __restrict__ accum,
                              int ofs, uint32_t key0, uint32_t key1,
                              int rp, char* sm) {
  constexpr int KSTEPS = KP / 32;
  constexpr int NCH = (K + 31) / 32;
  constexpr int PH = K / 2;            // k-pairs per sample per row
  constexpr int ITERS = PH / 4;        // genX iters (64*PH/256)
  constexpr int XSTR = KP + 8;         // bf16 elems per sample row (+16B pad)
  constexpr int XSTRU = XSTR / 2;      // uints per sample row
  constexpr int XROW_U = 64 * XSTRU;   // uints per data-row section
  constexpr int REGION = 2 * 64 * XSTR * 2;  // X both rows (bytes)
  // last chunk's nf=1 16-col subtile lies entirely in [K,K+16) padding
  constexpr bool SKIP1 = (K % 32) == 16;
  constexpr uint32_t HALF = 65536u * (uint32_t)K;

  const int tid = threadIdx.x;
  const int wave = tid >> 6;
  const int lane = tid & 63;
  const int quad = lane >> 4;
  const int l15 = lane & 15;
  const int row = wave >> 1;           // data-row of this wave (0/1)
  const int msub = (wave & 1) * 32;    // sample offset of this wave

  const int b0 = 4 * rp + ofs;
  const int b1 = 4 * (rp + 512) + ofs;

  uint32_t* Xu = (uint32_t*)sm;            // X both rows
  float* wvmax = (float*)(sm + REGION);    // 4 floats
  float* maxhm = wvmax + 4;                // 2 floats

  if (tid < 2) maxhm[tid] = 0.0f;

  // this wave's P base: quad selects k-subrow group, l15 selects column
  const float* Pr = Pp + (size_t)(row ? b1 : b0) * 16384 + quad * (8 * 128) + l15;

  for (int pass = 0; pass < 2; ++pass) {
    // ---- Phase A: generate X (both rows) straight to LDS as bf16
#pragma unroll
    for (int it = 0; it < ITERS; ++it) {
      int q = it * 256 + tid;
      int s_loc = q / PH;
      int k = 2 * (q - s_loc * PH);
      uint32_t ctr = (uint32_t)((rp * 128 + pass * 64 + s_loc) * K + k);
      uint32_t o0a, o1a, o0b, o1b;
      tf2x32(key0, key1, ctr, ctr + HALF, o0a, o1a);
      tf2x32(key0, key1, ctr + 1u, ctr + 1u + HALF, o0b, o1b);
      uint32_t idx = (uint32_t)(s_loc * XSTRU + (k >> 1));
      Xu[idx]          = cvt_pk_bf16(bits_to_normal(o0a), bits_to_normal(o0b));
      Xu[XROW_U + idx] = cvt_pk_bf16(bits_to_normal(o1a), bits_to_normal(o1b));
    }
    if constexpr (KP > K) {   // zero-pad k in [K,KP) for both rows
      constexpr int PADU = (KP - K) / 2;
      for (int p = tid; p < 2 * 64 * PADU; p += 256) {
        int rs = p / PADU;
        int r = p - rs * PADU;
        Xu[rs * XSTRU + K / 2 + r] = 0;
      }
    }
    __syncthreads();   // s1: X visible (cross-wave)

    // ---- X-frag load (MFMA B-operand) + per-lane X partial top-T (k-slice)
    bf16x8 ahi[2][KSTEPS];
#pragma unroll
    for (int f = 0; f < 2; ++f)
#pragma unroll
      for (int ks = 0; ks < KSTEPS; ++ks) {
        int off = ((row * 64 + msub + f * 16 + l15) * XSTR + ks * 32 + quad * 8) * 2;
        ahi[f][ks] = *(const bf16x8*)(sm + off);
      }
    float t5x[2][T];
#pragma unroll
    for (int f = 0; f < 2; ++f) {
#pragma unroll
      for (int q = 0; q < T; ++q) t5x[f][q] = 0.0f;
#pragma unroll
      for (int ks = 0; ks < KSTEPS; ++ks)
#pragma unroll
        for (int j = 0; j < 8; ++j)
          insT(t5x[f], fabsf(bf2f_s(ahi[f][ks][j])));
    }

    // ---- Y chunks, barrier-free: grouped issue-before-consume B loads
    float t5y[2][T];
#pragma unroll
    for (int f = 0; f < 2; ++f)
#pragma unroll
      for (int q = 0; q < T; ++q) t5y[f][q] = 0.0f;

#pragma unroll 1
    for (int c = 0; c < NCH; ++c) {
      const bool skip1 = SKIP1 && (c == NCH - 1);
      const float* bpc = Pr + c * 32;   // column base for this chunk
      f32x4 acc[2][2];
#pragma unroll
      for (int f = 0; f < 2; ++f)
#pragma unroll
        for (int nf = 0; nf < 2; ++nf) acc[f][nf] = (f32x4){0.f, 0.f, 0.f, 0.f};

#pragma unroll
      for (int kg = 0; kg < KSTEPS; kg += 2) {
        // group = 2 consecutive ks (1 for the odd tail); issue ALL its loads
        float rg[2][2][8];
#pragma unroll
        for (int s = 0; s < 2; ++s)
          if (kg + s < KSTEPS) {
            const float* bpk = bpc + (kg + s) * (32 * 128);
#pragma unroll
            for (int j = 0; j < 8; ++j) rg[s][0][j] = bpk[j * 128];
            if (!skip1) {
#pragma unroll
              for (int j = 0; j < 8; ++j) rg[s][1][j] = bpk[j * 128 + 16];
            }
          }
        // consume: cvt+MFMA (later tiles' loads still in flight)
#pragma unroll
        for (int s = 0; s < 2; ++s)
          if (kg + s < KSTEPS) {
            const int ks = kg + s;
            bf16x8 bh0 = pack8(rg[s][0]);
            acc[0][0] = __builtin_amdgcn_mfma_f32_16x16x32_bf16(bh0, ahi[0][ks], acc[0][0], 0, 0, 0);
            acc[1][0] = __builtin_amdgcn_mfma_f32_16x16x32_bf16(bh0, ahi[1][ks], acc[1][0], 0, 0, 0);
            if (!skip1) {
              bf16x8 bh1 = pack8(rg[s][1]);
              acc[0][1] = __builtin_amdgcn_mfma_f32_16x16x32_bf16(bh1, ahi[0][ks], acc[0][1], 0, 0, 0);
              acc[1][1] = __builtin_amdgcn_mfma_f32_16x16x32_bf16(bh1, ahi[1][ks], acc[1][1], 0, 0, 0);
            }
          }
      }

      // lane holds cols {c*32 + nf*16 + quad*4 + r} of sample f*16+l15
#pragma unroll
      for (int f = 0; f < 2; ++f)
#pragma unroll
        for (int r = 0; r < 4; ++r) {
          insT(t5y[f], fabsf(acc[f][0][r]));
          if (!skip1) insT(t5y[f], fabsf(acc[f][1][r]));
        }
    }

    // ---- merge: fold X partials, ONE quad butterfly (16,32), hm, wave max
    float wmax = 0.0f;
#pragma unroll
    for (int f = 0; f < 2; ++f) {
#pragma unroll
      for (int q = 0; q < T; ++q) insT(t5y[f], t5x[f][q]);
#pragma unroll
      for (int msk = 16; msk <= 32; msk <<= 1) {
        float o[T];
#pragma unroll
        for (int q = 0; q < T; ++q) o[q] = __shfl_xor(t5y[f][q], msk);
#pragma unroll
        for (int q = 0; q < T; ++q) insT(t5y[f], o[q]);
      }
      float hm = t5y[f][0] / (t5y[f][T - 1] + 1e-9f);
      wmax = fmaxf(wmax, hm);
    }
    // values replicated across quads; reduce across l15
#pragma unroll
    for (int msk = 1; msk <= 8; msk <<= 1)
      wmax = fmaxf(wmax, __shfl_xor(wmax, msk));
    if (lane == 0) wvmax[wave] = wmax;
    __syncthreads();   // s2: wvmax visible; also guards X reads vs next genX
    if (tid < 2)
      maxhm[tid] = fmaxf(maxhm[tid], fmaxf(wvmax[2 * tid], wvmax[2 * tid + 1]));
  }

  if (tid == 0) {
    float pen = fmaxf(maxhm[0] - yp[b0], 0.0f) + fmaxf(maxhm[1] - yp[b1], 0.0f);
    atomicAdd(&accum[0], pen);
    float d0 = log2f(fmaxf(yt[b0], 1e-9f)) - log2f(fmaxf(yp[b0], 1e-9f));
    float d1 = log2f(fmaxf(yt[b1], 1e-9f)) - log2f(fmaxf(yp[b1], 1e-9f));
    atomicAdd(&accum[1], fmaf(d0, d0, d1 * d1));
  }
}

struct ComboArgs {
  int ofs[4];
  uint32_t k0[4];
  uint32_t k1[4];
};

// max REGION (KP=128: 34816) + wvmax(16) + maxhm(8)
#define SM_BYTES (34816 + 16 + 8)

// (256,2): VGPR cap 256 -> compiler picks <=128, matching 4 blocks/CU
// (16 waves/CU; VGPR>64 caps at 16 waves/CU regardless of LDS).
__global__ __launch_bounds__(256, 2)
void viol_kernel(const float* __restrict__ Pp, const float* __restrict__ yp,
                 const float* __restrict__ yt, float* __restrict__ accum,
                 ComboArgs ca) {
  __shared__ __align__(16) char sm[SM_BYTES];
  // 512 contiguous blocks per combo (measured-good: L2 locality on P rows)
  int i = blockIdx.x >> 9;
  int rp = blockIdx.x & 511;
  switch (i) {
    case 0: process_combo< 80,  96, 3>(Pp, yp, yt, accum, ca.ofs[0], ca.k0[0], ca.k1[0], rp, sm); break;
    case 1: process_combo< 96,  96, 4>(Pp, yp, yt, accum, ca.ofs[1], ca.k0[1], ca.k1[1], rp, sm); break;
    case 2: process_combo<112, 128, 5>(Pp, yp, yt, accum, ca.ofs[2], ca.k0[2], ca.k1[2], rp, sm); break;
    default: process_combo<128, 128, 4>(Pp, yp, yt, accum, ca.ofs[3], ca.k0[3], ca.k1[3], rp, sm); break;
  }
}

__global__ void finalize_kernel(const float* __restrict__ accum, float* __restrict__ out) {
  if (threadIdx.x == 0 && blockIdx.x == 0) {
    float viol = accum[0] / 4096.0f;
    float lm = accum[1] / 4096.0f;
    out[0] = fmaf(0.5f, viol, lm);
    out[1] = lm;
    out[2] = viol;
  }
}

extern "C" void kernel_launch(void* const* d_in, const int* in_sizes, int n_in,
                              void* d_out, int out_size, void* d_ws, size_t ws_size,
                              hipStream_t stream) {
  const float* y_pred   = (const float*)d_in[0];
  const float* y_true   = (const float*)d_in[1];
  const float* P_padded = (const float*)d_in[2];
  float* accum = (float*)d_ws;
  float* out = (float*)d_out;

  hipMemsetAsync(accum, 0, 2 * sizeof(float), stream);

  // combos sorted as np.unique: (160,80,2)<-b%4==3, (192,96,3)<-1, (224,112,4)<-2, (256,128,3)<-0
  ComboArgs ca;
  const int ofs[4] = {3, 1, 2, 0};
  for (int i = 0; i < 4; ++i) {
    ca.ofs[i] = ofs[i];
    uint32_t o0, o1;
    tf2x32(0u, 42u, 0u, (uint32_t)i, o0, o1);  // fold_in(key(42), i)
    ca.k0[i] = o0;
    ca.k1[i] = o1;
  }

  viol_kernel<<<2048, 256, 0, stream>>>(P_padded, y_pred, y_true, accum, ca);
  finalize_kernel<<<1, 64, 0, stream>>>(accum, out);
}